// Round 2
// 8705.860 us; speedup vs baseline: 1.3784x; 1.3784x over previous
//
#include <hip/hip_runtime.h>
#include <cstdint>
#include <cstddef>

constexpr int BATCH = 32;
constexpr int SEQ   = 128;
constexpr int VOC   = 32000;
constexpr int EMB   = 400;
constexpr int MDEF  = 512;
constexpr int HID   = 1152;

__device__ __forceinline__ float sigf(float x) { return 1.0f / (1.0f + expf(-x)); }

// ---------------------------------------------------------------------------
// Generic fp32 tiled GEMM: C[M,N] = Arows @ B (+bias1+bias2)
//   A row-major [M,lda] (or gathered embedding rows if GATHER)
//   TRANSB: Bsrc is [N,K] row-major (use rows as columns);  else Bsrc is [K,N]
//   PERMC : output row m=tb=(t*32+b) is stored at row (b*SEQ+t)
// 128x128 tile, 256 threads, 8x8 micro-tile, TK=16.
// ---------------------------------------------------------------------------
template<bool TRANSB, bool GATHER, bool PERMC>
__global__ __launch_bounds__(256)
void gemm128x128(const float* __restrict__ A, int lda,
                 const float* __restrict__ Bsrc,
                 const float* __restrict__ b1, const float* __restrict__ b2,
                 const int* __restrict__ ids, const float* __restrict__ gsrc,
                 float* __restrict__ C, int ldc, int N, int K)
{
    __shared__ float As[16][132];
    __shared__ float Bs[16][128];
    const int t  = threadIdx.x;
    const int n0 = blockIdx.x * 128;
    const int m0 = blockIdx.y * 128;
    const int tx = t & 15, ty = t >> 4;

    const int mA = t >> 2, kq = t & 3;      // A loader: rows mA, mA+64; 4 k's
    const float* arow0;
    const float* arow1;
    if (GATHER) {
        int r0 = m0 + mA, r1 = r0 + 64;     // rows are tb = t_idx*32 + b
        arow0 = gsrc + (size_t)ids[(r0 & 31) * SEQ + (r0 >> 5)] * EMB;
        arow1 = gsrc + (size_t)ids[(r1 & 31) * SEQ + (r1 >> 5)] * EMB;
    } else {
        arow0 = A + (size_t)(m0 + mA) * lda;
        arow1 = arow0 + (size_t)64 * lda;
    }

    float acc[8][8];
#pragma unroll
    for (int i = 0; i < 8; ++i)
#pragma unroll
        for (int j = 0; j < 8; ++j) acc[i][j] = 0.0f;

    const int nB = t >> 2;                   // TRANSB loader row
    const int kB = t >> 5, n4 = (t & 31) * 4; // non-trans loader

    for (int k0 = 0; k0 < K; k0 += 16) {
        float4 a0 = *(const float4*)(arow0 + k0 + kq * 4);
        float4 a1 = *(const float4*)(arow1 + k0 + kq * 4);
        float4 bv0 = make_float4(0.f, 0.f, 0.f, 0.f);
        float4 bv1 = make_float4(0.f, 0.f, 0.f, 0.f);
        if (TRANSB) {
            if (n0 + nB < N)
                bv0 = *(const float4*)(Bsrc + (size_t)(n0 + nB) * K + k0 + kq * 4);
            if (n0 + nB + 64 < N)
                bv1 = *(const float4*)(Bsrc + (size_t)(n0 + nB + 64) * K + k0 + kq * 4);
        } else {
            bv0 = *(const float4*)(Bsrc + (size_t)(k0 + kB) * N + n0 + n4);
            bv1 = *(const float4*)(Bsrc + (size_t)(k0 + kB + 8) * N + n0 + n4);
        }
        __syncthreads();
        As[kq * 4 + 0][mA] = a0.x; As[kq * 4 + 1][mA] = a0.y;
        As[kq * 4 + 2][mA] = a0.z; As[kq * 4 + 3][mA] = a0.w;
        As[kq * 4 + 0][mA + 64] = a1.x; As[kq * 4 + 1][mA + 64] = a1.y;
        As[kq * 4 + 2][mA + 64] = a1.z; As[kq * 4 + 3][mA + 64] = a1.w;
        if (TRANSB) {
            Bs[kq * 4 + 0][nB] = bv0.x; Bs[kq * 4 + 1][nB] = bv0.y;
            Bs[kq * 4 + 2][nB] = bv0.z; Bs[kq * 4 + 3][nB] = bv0.w;
            Bs[kq * 4 + 0][nB + 64] = bv1.x; Bs[kq * 4 + 1][nB + 64] = bv1.y;
            Bs[kq * 4 + 2][nB + 64] = bv1.z; Bs[kq * 4 + 3][nB + 64] = bv1.w;
        } else {
            *(float4*)&Bs[kB][n4]     = bv0;
            *(float4*)&Bs[kB + 8][n4] = bv1;
        }
        __syncthreads();
#pragma unroll
        for (int kk = 0; kk < 16; ++kk) {
            float4 xa = *(const float4*)&As[kk][ty * 8];
            float4 xb = *(const float4*)&As[kk][ty * 8 + 4];
            float4 ya = *(const float4*)&Bs[kk][tx * 8];
            float4 yb = *(const float4*)&Bs[kk][tx * 8 + 4];
            float av[8] = {xa.x, xa.y, xa.z, xa.w, xb.x, xb.y, xb.z, xb.w};
            float bw[8] = {ya.x, ya.y, ya.z, ya.w, yb.x, yb.y, yb.z, yb.w};
#pragma unroll
            for (int i = 0; i < 8; ++i)
#pragma unroll
                for (int j = 0; j < 8; ++j) acc[i][j] += av[i] * bw[j];
        }
    }

    float bias[8];
#pragma unroll
    for (int j = 0; j < 8; ++j) {
        int n = n0 + tx * 8 + j;
        float v = 0.0f;
        if (n < N) {
            if (b1) v += b1[n];
            if (b2) v += b2[n];
        }
        bias[j] = v;
    }
    const bool g0 = (n0 + tx * 8) < N;
    const bool g1 = (n0 + tx * 8 + 4) < N;
#pragma unroll
    for (int i = 0; i < 8; ++i) {
        int m = m0 + ty * 8 + i;
        size_t crow = PERMC ? ((size_t)(m & 31) * SEQ + (m >> 5)) : (size_t)m;
        float* cp = C + crow * (size_t)ldc + n0 + tx * 8;
        if (g0) {
            float4 v = make_float4(acc[i][0] + bias[0], acc[i][1] + bias[1],
                                   acc[i][2] + bias[2], acc[i][3] + bias[3]);
            *(float4*)cp = v;
        }
        if (g1) {
            float4 v = make_float4(acc[i][4] + bias[4], acc[i][5] + bias[5],
                                   acc[i][6] + bias[6], acc[i][7] + bias[7]);
            *(float4*)(cp + 4) = v;
        }
    }
}

// ---------------------------------------------------------------------------
// Persistent LSTM recurrence. One launch per layer, grid=256 blocks (1/CU,
// forced by LDS size), grid barrier between time steps.
//
// Barrier protocol (this revision): each y[tt] address range is written
// exactly once (step tt) and read exactly once (step tt+1) within the
// dispatch, so no XCD can ever hold a STALE cached line for it — provided
// the writes are L3-visible at store time. Therefore:
//   - y exchange stores: relaxed agent-scope atomic stores (write-through
//     past L2 to the coherence point; nothing dirty left in L2),
//   - arrive: relaxed agent atomic add (NO release -> no buffer_wbl2),
//   - release: relaxed spin, NO __threadfence (no L2/L1 invalidate; plain
//     cached float4 h loads stay legal and regain intra-XCD L2 reuse).
// Previous version did release+acquire per block per step = 256 L2
// writeback walks + 256 full L2 invalidates per step, which destroyed all
// L2 locality (FETCH_SIZE 364 MB vs 75 MB of pre) and cost ~25 us/step.
// ---------------------------------------------------------------------------
template<int HD, int NJ>
__device__ void rec_path(const float* __restrict__ Whh,
                         const float* __restrict__ pre,
                         const float* __restrict__ h0,
                         const float* __restrict__ c0,
                         float* __restrict__ y,
                         float* __restrict__ hN,
                         float* __restrict__ cN,
                         unsigned* __restrict__ ctr,
                         int j0, float* wl, float* part)
{
    constexpr int HDp = HD + 4;
    constexpr int NR  = 4 * NJ;
    constexpr int NCH = HD / 4;
    constexpr int G4  = 4 * HD;
    const int t = threadIdx.x;

    // stage Whh slice: dst row r = g*NJ + jj  <- Whh row (g*HD + j0 + jj)
    for (int idx = t; idx < NR * NCH; idx += 256) {
        int r = idx / NCH, kc = idx - r * NCH;
        int g = r / NJ, jj = r - g * NJ;
        *(float4*)&wl[r * HDp + 4 * kc] =
            *(const float4*)&Whh[(size_t)(g * HD + j0 + jj) * HD + 4 * kc];
    }

    const int cb = t & 31, cjj = t >> 5;        // combine mapping
    const bool is_comb = (cjj < NJ);
    float cstate = is_comb ? c0[cb * HD + j0 + cjj] : 0.0f;

    const int ks = t & 31, bq = t >> 5;         // dot mapping
    const int b0 = bq * 4;
    unsigned bail = 0;

    __syncthreads();

    for (int tt = 0; tt < SEQ; ++tt) {
        // prefetch this step's pre-activations (used only after the dots)
        float p0 = 0.f, p1 = 0.f, p2 = 0.f, p3 = 0.f;
        if (is_comb) {
            const float* pr = pre + ((size_t)tt * BATCH + cb) * G4 + (j0 + cjj);
            p0 = pr[0]; p1 = pr[HD]; p2 = pr[2 * HD]; p3 = pr[3 * HD];
        }
        const float* hp = tt ? (y + (size_t)(tt - 1) * BATCH * HD) : h0;

        float acc[4][NR];
#pragma unroll
        for (int c = 0; c < 4; ++c)
#pragma unroll
            for (int r = 0; r < NR; ++r) acc[c][r] = 0.0f;

        for (int kc = ks; kc < NCH; kc += 32) {
            const int k = 4 * kc;
            float4 hv[4];
#pragma unroll
            for (int c = 0; c < 4; ++c)
                hv[c] = *(const float4*)&hp[(size_t)(b0 + c) * HD + k];
#pragma unroll
            for (int r = 0; r < NR; ++r) {
                float4 wv = *(const float4*)&wl[r * HDp + k];
#pragma unroll
                for (int c = 0; c < 4; ++c) {
                    acc[c][r] += hv[c].x * wv.x;
                    acc[c][r] += hv[c].y * wv.y;
                    acc[c][r] += hv[c].z * wv.z;
                    acc[c][r] += hv[c].w * wv.w;
                }
            }
        }
        // reduce ks 32 -> 8 partials
#pragma unroll
        for (int c = 0; c < 4; ++c)
#pragma unroll
            for (int r = 0; r < NR; ++r) {
                acc[c][r] += __shfl_xor(acc[c][r], 1, 64);
                acc[c][r] += __shfl_xor(acc[c][r], 2, 64);
            }
        if ((ks & 3) == 0) {
            const int pidx = ks >> 2;
#pragma unroll
            for (int c = 0; c < 4; ++c)
#pragma unroll
                for (int r = 0; r < NR; ++r) {
                    int g = r / NJ, jj = r - g * NJ;
                    part[(((b0 + c) * NJ + jj) * 4 + g) * 8 + pidx] = acc[c][r];
                }
        }
        __syncthreads();
        if (is_comb) {
            const float* pp = &part[((size_t)(cb * NJ + cjj) * 4) * 8];
            float s[4];
#pragma unroll
            for (int g = 0; g < 4; ++g) {
                float4 u = *(const float4*)&pp[g * 8];
                float4 v = *(const float4*)&pp[g * 8 + 4];
                s[g] = ((u.x + u.y) + (u.z + u.w)) + ((v.x + v.y) + (v.z + v.w));
            }
            float iv = s[0] + p0, fv = s[1] + p1, gv = s[2] + p2, ov = s[3] + p3;
            cstate = sigf(fv) * cstate + sigf(iv) * tanhf(gv);
            float hh = sigf(ov) * tanhf(cstate);
            // write-through to the coherence point so readers on other XCDs
            // see it without any release/acquire cache maintenance (each
            // address is written exactly once per dispatch).
            __hip_atomic_store(&y[(size_t)tt * BATCH * HD + cb * HD + (j0 + cjj)],
                               hh, __ATOMIC_RELAXED, __HIP_MEMORY_SCOPE_AGENT);
            if (tt == SEQ - 1) {
                hN[cb * HD + j0 + cjj] = hh;
                cN[cb * HD + j0 + cjj] = cstate;
            }
        }
        __syncthreads();   // drains vmcnt(0) per wave before thread 0 arrives
        if (tt + 1 < SEQ) {
            if (t == 0) {
                __hip_atomic_fetch_add(ctr, 1u, __ATOMIC_RELAXED,
                                       __HIP_MEMORY_SCOPE_AGENT);
                const unsigned tgt = 256u * (unsigned)(tt + 1);
                if (!bail) {
                    unsigned spins = 0;
                    while (__hip_atomic_load(ctr, __ATOMIC_RELAXED,
                                             __HIP_MEMORY_SCOPE_AGENT) < tgt) {
                        __builtin_amdgcn_s_sleep(2);
                        if (++spins > (1u << 24)) { bail = 1; break; }
                    }
                }
                // no __threadfence: y-exchange lines cannot be stale anywhere
                // (unique address per step + write-through stores).
            }
            __syncthreads();
        }
    }
}

__global__ __launch_bounds__(256, 1)
void lstm_rec_big(const float* __restrict__ Whh, const float* __restrict__ pre,
                  const float* __restrict__ h0, const float* __restrict__ c0,
                  float* __restrict__ y, float* __restrict__ hN,
                  float* __restrict__ cN, unsigned* __restrict__ ctr)
{
    extern __shared__ float smem[];
    float* wl   = smem;
    float* part = smem + 20 * (HID + 4);   // max NJ=5 weight slab
    const int bl = blockIdx.x;
    if (bl < 128)
        rec_path<HID, 4>(Whh, pre, h0, c0, y, hN, cN, ctr, 4 * bl, wl, part);
    else
        rec_path<HID, 5>(Whh, pre, h0, c0, y, hN, cN, ctr, 512 + 5 * (bl - 128), wl, part);
}

__global__ __launch_bounds__(256, 1)
void lstm_rec_small(const float* __restrict__ Whh, const float* __restrict__ pre,
                    const float* __restrict__ h0, const float* __restrict__ c0,
                    float* __restrict__ y, float* __restrict__ hN,
                    float* __restrict__ cN, unsigned* __restrict__ ctr)
{
    extern __shared__ float smem[];
    float* wl   = smem;
    float* part = smem + 8 * (EMB + 4);
    const int bl = blockIdx.x;
    if (bl < 144)
        rec_path<EMB, 2>(Whh, pre, h0, c0, y, hN, cN, ctr, 2 * bl, wl, part);
    else
        rec_path<EMB, 1>(Whh, pre, h0, c0, y, hN, cN, ctr, 288 + (bl - 144), wl, part);
}

// ---------------------------------------------------------------------------
extern "C" void kernel_launch(void* const* d_in, const int* in_sizes, int n_in,
                              void* d_out, int out_size, void* d_ws, size_t ws_size,
                              hipStream_t stream)
{
    const int*   ids  = (const int*)  d_in[0];
    const float* emb  = (const float*)d_in[1];
    const float* dW   = (const float*)d_in[2];
    const float* db   = (const float*)d_in[3];
    const float* Wih0 = (const float*)d_in[4];
    const float* Whh0 = (const float*)d_in[5];
    const float* bih0 = (const float*)d_in[6];
    const float* bhh0 = (const float*)d_in[7];
    const float* h00  = (const float*)d_in[8];
    const float* c00  = (const float*)d_in[9];
    const float* Wih1 = (const float*)d_in[10];
    const float* Whh1 = (const float*)d_in[11];
    const float* bih1 = (const float*)d_in[12];
    const float* bhh1 = (const float*)d_in[13];
    const float* h01  = (const float*)d_in[14];
    const float* c01  = (const float*)d_in[15];
    const float* Wih2 = (const float*)d_in[16];
    const float* Whh2 = (const float*)d_in[17];
    const float* bih2 = (const float*)d_in[18];
    const float* bhh2 = (const float*)d_in[19];
    const float* h02  = (const float*)d_in[20];
    const float* c02  = (const float*)d_in[21];

    float* out    = (float*)d_out;
    float* logits = out;
    float* h0f = out + (size_t)131072000;
    float* c0f = h0f + 36864;
    float* h1f = c0f + 36864;
    float* c1f = h1f + 36864;
    float* h2f = c1f + 36864;
    float* c2f = h2f + 12800;

    // scratch inside d_out (all dead before the logits GEMM overwrites them)
    float* P  = out;                        // pre-activations, up to 4096x4608
    float* x0 = out + (size_t)18874368;     // 4096x512
    float* y0 = out + (size_t)20971520;     // 4096x1152
    float* y1 = out + (size_t)25690112;     // 4096x1152
    // d_ws: barrier counters + y2 (read by logits GEMM, so must not alias out)
    unsigned* ctr = (unsigned*)d_ws;
    float* y2 = (float*)d_ws + 64;          // 4096x400

    (void)in_sizes; (void)n_in; (void)out_size; (void)ws_size;

    (void)hipMemsetAsync(ctr, 0, 256, stream);

    (void)hipFuncSetAttribute((const void*)lstm_rec_big,
        hipFuncAttributeMaxDynamicSharedMemorySize, 116736);
    (void)hipFuncSetAttribute((const void*)lstm_rec_small,
        hipFuncAttributeMaxDynamicSharedMemorySize, 90112);

    dim3 blk(256);

    // 1) embedding gather + DeFINE projection -> x0 [tb, 512]
    gemm128x128<false, true, false><<<dim3(4, 32), blk, 0, stream>>>(
        nullptr, 0, dW, db, nullptr, ids, emb, x0, MDEF, MDEF, EMB);

    // 2) layer0 input GEMM -> P [tb, 4608]
    gemm128x128<true, false, false><<<dim3(36, 32), blk, 0, stream>>>(
        x0, MDEF, Wih0, bih0, bhh0, nullptr, nullptr, P, 4 * HID, 4 * HID, MDEF);

    // 3) layer0 recurrence -> y0 (+ finals)
    lstm_rec_big<<<dim3(256), blk, 112960, stream>>>(
        Whh0, P, h00, c00, y0, h0f, c0f, ctr + 0);

    // 4) layer1 input GEMM
    gemm128x128<true, false, false><<<dim3(36, 32), blk, 0, stream>>>(
        y0, HID, Wih1, bih1, bhh1, nullptr, nullptr, P, 4 * HID, 4 * HID, HID);

    // 5) layer1 recurrence -> y1
    lstm_rec_big<<<dim3(256), blk, 112960, stream>>>(
        Whh1, P, h01, c01, y1, h1f, c1f, ctr + 1);

    // 6) layer2 input GEMM (G=1600)
    gemm128x128<true, false, false><<<dim3(13, 32), blk, 0, stream>>>(
        y1, HID, Wih2, bih2, bhh2, nullptr, nullptr, P, 1600, 1600, HID);

    // 7) layer2 recurrence -> y2 (in d_ws)
    lstm_rec_small<<<dim3(256), blk, 86016, stream>>>(
        Whh2, P, h02, c02, y2, h2f, c2f, ctr + 2);

    // 8) tied-embedding logits: [4096,400] @ emb^T -> [b*T, 32000]
    gemm128x128<true, false, true><<<dim3(250, 32), blk, 0, stream>>>(
        y2, EMB, emb, nullptr, nullptr, nullptr, nullptr, logits, VOC, VOC, EMB);
}